// Round 5
// baseline (2672.037 us; speedup 1.0000x reference)
//
#include <hip/hip_runtime.h>
#include <math.h>

constexpr int kB  = 256;
constexpr int kT  = 512;
constexpr int kNS = 64;
constexpr int kH  = 128;
constexpr int kNT = 768;      // R14: threads/block = K rows (1:1), 12 waves

// WhhT rows 0..255 cached in LDS (fp32), padded to 132 floats/row: lane bank
// = 4*(u+k4) % 32 -> all 32 banks hit uniformly per b128 read.
constexpr int kWRowsLds = 256;
constexpr int kWPad     = 132;

__device__ __forceinline__ float sigmoidf_(float v) { return 1.0f / (1.0f + __expf(-v)); }
__device__ __forceinline__ float dot4(float4 a, float4 b) {
    return a.x*b.x + a.y*b.y + a.z*b.z + a.w*b.w;
}

// ---- DPP cross-lane reduce (4 VALU DPP + 2 DS ops) ------------------------
template <int CTRL>
__device__ __forceinline__ float dppf(float x) {
    return __int_as_float(__builtin_amdgcn_mov_dpp(__float_as_int(x), CTRL, 0xf, 0xf, true));
}
__device__ __forceinline__ float red_max64(float x) {
    x = fmaxf(x, dppf<0xB1>(x));
    x = fmaxf(x, dppf<0x4E>(x));
    x = fmaxf(x, dppf<0x124>(x));
    x = fmaxf(x, dppf<0x128>(x));
    x = fmaxf(x, __shfl_xor(x, 16, 64));
    x = fmaxf(x, __shfl_xor(x, 32, 64));
    return x;
}
__device__ __forceinline__ float red_sum64(float x) {
    x += dppf<0xB1>(x);
    x += dppf<0x4E>(x);
    x += dppf<0x124>(x);
    x += dppf<0x128>(x);
    x += __shfl_xor(x, 16, 64);
    x += __shfl_xor(x, 32, 64);
    return x;
}

// One-time: transpose Whh[128][384] -> WhhT[384][128] in d_ws.
extern "C" __global__ void __launch_bounds__(256)
whh_transpose(const float* __restrict__ Whh, float* __restrict__ WhhT) {
    const int o = blockIdx.x * 256 + threadIdx.x;   // 0..49151
    const int j = o >> 7, k = o & 127;
    WhhT[o] = Whh[k * 384 + j];
}

// One block (768 threads = 12 waves) per batch row. 3 barriers/step.
//   PA: every thread computes ONE K row (row = tid) + per-wave max
//   PB: einsum partial per wave-chunk (lane = n) + GRU (threads 0-127)
//   PE: w0 tail | w1 x/y prefetch | w2-5 gh rows 0..255 (LDS, 1 thr/row)
//       | w6-9 gh rows 256..383 (L2, 2 thr/row halves) | w10-11 idle
extern "C" __global__ void __launch_bounds__(768, 3)
disc_kernel(const float* __restrict__ x,   const float* __restrict__ y,
            const float* __restrict__ U,   const float* __restrict__ S,
            const float* __restrict__ A,   const float* __restrict__ Wih,
            const float* __restrict__ bih, const float* __restrict__ bhh,
            const float* __restrict__ Wd,  const float* __restrict__ bd,
            const float* __restrict__ WhhT,
            float* __restrict__ out_o,  float* __restrict__ out_p)
{
    const int b    = blockIdx.x;
    const int tid  = threadIdx.x;
    const int lane = tid & 63;
    const int wid  = tid >> 6;                        // 0..11

    __shared__ __align__(16) float sh_K[768];
    __shared__ __align__(16) float sh_part[768];
    __shared__ __align__(16) float sh_gh[256];        // r,z rows (LDS-weight rows)
    __shared__ __align__(16) float sh_ghn[2][128];    // n-gate rows, 2 L2 partials
    __shared__ __align__(16) float sh_h[kH];          // single buffer (RMW by owner)
    __shared__ __align__(16) float sh_s[kNS];
    __shared__ __align__(16) float sh_Wih[4 * 384];
    __shared__ __align__(16) float sh_bih[384];
    __shared__ __align__(16) float sh_bhh[384];
    __shared__ float sh_Wd[384];
    __shared__ float sh_bd[4];
    __shared__ float sh_enc[12];                      // per-wave max of K
    __shared__ __align__(16) float sh_xt[4];
    __shared__ float sh_x2, sh_s2, sh_err;
    __shared__ float sh_yt[2];
    // 256 x 132 fp32 = 135168 B; block total ~152 KB (<=160 KB, 1 blk/CU)
    __shared__ __align__(16) float sh_W[kWRowsLds * kWPad];

    // ---- Persistent register caches (~133 floats; cap 168 via l.b.(768,3)) -
    const float4* S4 = reinterpret_cast<const float4*>(S);
    const float4* U4 = reinterpret_cast<const float4*>(U);

    float4 Sa[16]; float4 Ua; float Ca;               // K row = tid
    {
        float ss = 0.f;
#pragma unroll
        for (int j = 0; j < 16; ++j) { Sa[j] = S4[tid * 16 + j]; ss += dot4(Sa[j], Sa[j]); }
        Ua = U4[tid];
        Ca = -0.5f * (dot4(Ua, Ua) + ss);
    }
    // Einsum A cache: wave wid owns K rows [64*wid, 64*wid+64), lane = n.
    float A1[64];
#pragma unroll
    for (int dd = 0; dd < 64; ++dd)
        A1[dd] = A[(wid * 64 + dd) * 64 + lane];

    // PE-wave0 persistent gate state
    float g0 = 0.3333f, g1 = 0.3333f, g2 = 0.3334f;

    // ---- LDS preload -----------------------------------------------------
    for (int i = tid; i < 1536; i += kNT) sh_Wih[i] = Wih[i];
    for (int i = tid; i < 384; i += kNT) {
        sh_bih[i] = bih[i];
        sh_bhh[i] = bhh[i];
        sh_Wd[i]  = (i < 381) ? Wd[i] : 0.f;          // zero-pad rows 127*3..383
    }
    for (int i = tid; i < 256; i += kNT) sh_gh[i] = bhh[i];   // gh(t=0), h=0
    if (tid < 128) { sh_ghn[0][tid] = 0.f; sh_ghn[1][tid] = 0.f; sh_h[tid] = 0.f; }
    // One-time WhhT rows 0..255 -> padded LDS
    for (int i4 = tid; i4 < kWRowsLds * 32; i4 += kNT) {
        const int r = i4 >> 5, c4 = i4 & 31;
        reinterpret_cast<float4*>(sh_W + r * kWPad)[c4] =
            reinterpret_cast<const float4*>(WhhT)[i4];
    }
    if (tid < 3) sh_bd[tid] = bd[tid];
    if (tid < kNS) sh_s[tid] = 0.f;
    if (tid == 0) {
        sh_err = 1.0f; sh_s2 = 0.f;
        float4 xv = reinterpret_cast<const float4*>(x)[(size_t)b * kT];
        reinterpret_cast<float4*>(sh_xt)[0] = xv;
        sh_x2 = dot4(xv, xv);
        sh_yt[0] = y[(size_t)b * kT];
    }
    __syncthreads();

    for (int t = 0; t < kT; ++t) {
        const int par  = t & 1;
        const int par1 = (t + 1) & 1;

        // ===== PA: one K row per thread ====================================
        {
            const float scal = -0.5f * (sh_x2 + sh_s2);
            const float4 xt4 = reinterpret_cast<const float4*>(sh_xt)[0];
            const float4* s4 = reinterpret_cast<const float4*>(sh_s);
            float da0 = 0.f, da1 = 0.f;
#pragma unroll
            for (int j = 0; j < 8; ++j) {              // s broadcast, read once
                da0 += dot4(s4[j],     Sa[j]);
                da1 += dot4(s4[8 + j], Sa[8 + j]);
            }
            const float kk = __expf(scal + Ca + dot4(xt4, Ua) + da0 + da1);
            sh_K[tid] = kk;
            const float m = red_max64(kk);
            if (lane == 0) sh_enc[wid] = m;
        }
        __syncthreads();                                  // (1)

        // ===== PB: einsum partial (all waves) + GRU (threads 0-127) ========
        {
            const float4* K4 = reinterpret_cast<const float4*>(sh_K + wid * 64);
            float acc0 = 0.f, acc1 = 0.f;                 // 2 chains for ILP
#pragma unroll
            for (int j = 0; j < 16; j += 2) {             // wave-uniform broadcast
                const float4 k0 = K4[j], k1 = K4[j + 1];
                acc0 += k0.x*A1[4*j]   + k0.y*A1[4*j+1] + k0.z*A1[4*j+2] + k0.w*A1[4*j+3];
                acc1 += k1.x*A1[4*j+4] + k1.y*A1[4*j+5] + k1.z*A1[4*j+6] + k1.w*A1[4*j+7];
            }
            sh_part[tid] = acc0 + acc1;
        }
        if (tid < 128) {
            const float e0 = fmaxf(fmaxf(sh_enc[0], sh_enc[1]),  fmaxf(sh_enc[2],  sh_enc[3]));
            const float e1 = fmaxf(fmaxf(sh_enc[4], sh_enc[5]),  fmaxf(sh_enc[6],  sh_enc[7]));
            const float e2 = fmaxf(fmaxf(sh_enc[8], sh_enc[9]),  fmaxf(sh_enc[10], sh_enc[11]));
            const float er = sh_err;
            const int j = tid;
            const float gir = sh_bih[j]       + e0*sh_Wih[j]        + e1*sh_Wih[384 + j]
                                              + e2*sh_Wih[768 + j]  + er*sh_Wih[1152 + j];
            const float giz = sh_bih[128 + j] + e0*sh_Wih[128 + j]  + e1*sh_Wih[512 + j]
                                              + e2*sh_Wih[896 + j]  + er*sh_Wih[1280 + j];
            const float gin = sh_bih[256 + j] + e0*sh_Wih[256 + j]  + e1*sh_Wih[640 + j]
                                              + e2*sh_Wih[1024 + j] + er*sh_Wih[1408 + j];
            const float hn_ = sh_bhh[256 + j] + sh_ghn[0][j] + sh_ghn[1][j];
            const float r  = sigmoidf_(gir + sh_gh[j]);
            const float z  = sigmoidf_(giz + sh_gh[128 + j]);
            const float nn = tanhf(gin + r * hn_);
            sh_h[j] = (1.f - z) * nn + z * sh_h[j];       // RMW by owner thread
        }
        __syncthreads();                                  // (2)

        // ===== PE: w0 tail | w1 pref | w2-5 gh LDS | w6-9 gh L2 ============
        if (wid == 0) {
            const float hA = sh_h[lane];
            const float hB = sh_h[64 + lane];
            const float theta = sigmoidf_(sh_h[127]);
            float l0 = hA * sh_Wd[lane*3+0] + hB * sh_Wd[(64+lane)*3+0];
            float l1 = hA * sh_Wd[lane*3+1] + hB * sh_Wd[(64+lane)*3+1];
            float l2 = hA * sh_Wd[lane*3+2] + hB * sh_Wd[(64+lane)*3+2];
            l0 = red_sum64(l0);
            l1 = red_sum64(l1);
            l2 = red_sum64(l2);
            l0 += sh_bd[0]; l1 += sh_bd[1]; l2 += sh_bd[2];
            const float mx = fmaxf(l0, fmaxf(l1, l2));
            const float x0 = __expf(l0 - mx), x1 = __expf(l1 - mx), x2 = __expf(l2 - mx);
            const float inv = theta / (x0 + x1 + x2);
            const float omt = 1.f - theta;
            g0 = x0*inv + g0*omt;
            g1 = x1*inv + g1*omt;
            g2 = x2*inv + g2*omt;
            const float ns0 = (sh_part[lane]       + sh_part[64 + lane])
                            + (sh_part[128 + lane] + sh_part[192 + lane]);
            const float ns1 = (sh_part[256 + lane] + sh_part[320 + lane])
                            + (sh_part[384 + lane] + sh_part[448 + lane]);
            const float ns2 = (sh_part[512 + lane] + sh_part[576 + lane])
                            + (sh_part[640 + lane] + sh_part[704 + lane]);
            const float sn = g0*ns0 + g1*ns1 + g2*ns2;
            sh_s[lane] = sn;
            if (lane == 0)
                out_p[(size_t)b * kT + t] = g0*(1.f-g0) + g1*(1.f-g1) + g2*(1.f-g2);
            if (lane == 63) {
                out_o[(size_t)b * kT + t] = sn;
                sh_err = sn - sh_yt[par];
            }
            const float ss = red_sum64(sn * sn);
            if (lane == 0) sh_s2 = ss;
        } else if (wid == 1) {
            if (lane == 0 && (t + 1) < kT) {
                float4 xv = reinterpret_cast<const float4*>(x)[(size_t)b * kT + t + 1];
                reinterpret_cast<float4*>(sh_xt)[0] = xv;
                sh_x2 = dot4(xv, xv);
                sh_yt[par1] = y[(size_t)b * kT + t + 1];
            }
        } else if (wid < 6) {                             // waves 2-5: rows 0..255 (LDS)
            const int u = tid - 128;                      // 0..255, 1 thread/row
            const float4* W4 = reinterpret_cast<const float4*>(sh_W + u * kWPad);
            const float4* h4 = reinterpret_cast<const float4*>(sh_h);
            float ga = sh_bhh[u], gb = 0.f;               // 2 chains for ILP
#pragma unroll 8
            for (int k4 = 0; k4 < 32; k4 += 2) {
                ga += dot4(h4[k4],     W4[k4]);
                gb += dot4(h4[k4 + 1], W4[k4 + 1]);
            }
            sh_gh[u] = ga + gb;
        } else if (wid < 10) {                            // waves 6-9: rows 256..383 (L2)
            const int v    = tid - 384;                   // 0..255, 2 threads/row
            const int u    = 256 + (v >> 1);
            const int half = v & 1;
            const float4* W4 = reinterpret_cast<const float4*>(WhhT) + u * 32 + half * 16;
            const float4* h4 = reinterpret_cast<const float4*>(sh_h) + half * 16;
            float ga = 0.f, gb = 0.f;
#pragma unroll 8
            for (int k4 = 0; k4 < 16; k4 += 2) {
                ga += dot4(h4[k4],     W4[k4]);
                gb += dot4(h4[k4 + 1], W4[k4 + 1]);
            }
            sh_ghn[half][u - 256] = ga + gb;              // GRU adds both halves
        }
        // waves 10-11: idle in PE (arrive early, hide barrier skew)
        __syncthreads();                                  // (3)
    }
}

extern "C" void kernel_launch(void* const* d_in, const int* in_sizes, int n_in,
                              void* d_out, int out_size, void* d_ws, size_t ws_size,
                              hipStream_t stream)
{
    const float* x   = (const float*)d_in[0];
    const float* y   = (const float*)d_in[1];
    const float* U   = (const float*)d_in[2];
    const float* S   = (const float*)d_in[3];
    const float* A   = (const float*)d_in[4];
    const float* Wih = (const float*)d_in[5];
    const float* Whh = (const float*)d_in[6];
    const float* bih = (const float*)d_in[7];
    const float* bhh = (const float*)d_in[8];
    const float* Wd  = (const float*)d_in[9];
    const float* bd  = (const float*)d_in[10];

    float* WhhT  = (float*)d_ws;                 // 49152 floats = 192 KB scratch
    float* out_o = (float*)d_out;                // (B, T) preds
    float* out_p = out_o + kB * kT;              // (B, T, 1) penalties

    hipLaunchKernelGGL(whh_transpose, dim3(192), dim3(256), 0, stream, Whh, WhhT);
    hipLaunchKernelGGL(disc_kernel, dim3(kB), dim3(kNT), 0, stream,
                       x, y, U, S, A, Wih, bih, bhh, Wd, bd, WhhT, out_o, out_p);
}